// Round 10
// baseline (204.386 us; speedup 1.0000x reference)
//
#include <hip/hip_runtime.h>
#include <cstdint>
#include <cstddef>

#define N 4096
#define M 4096
#define DT 0.01f

#define BM 128
#define BN 128
#define BK 64   // K elements staged per barrier pair (2 MFMA half-phases)

#define HRS_STRIDE 4224  // shorts per shift-plane (4096 + 128 pad); 8448 B, 16-B aligned

typedef short bf16x8 __attribute__((ext_vector_type(8)));
typedef float f32x4 __attribute__((ext_vector_type(4)));

__device__ __forceinline__ unsigned short f2bf(float f) {
  unsigned u = __builtin_bit_cast(unsigned, f);
  return (unsigned short)((u + 0x7fffu + ((u >> 16) & 1u)) >> 16);  // RNE
}
__device__ __forceinline__ float bf2f(unsigned short u) {
  return __builtin_bit_cast(float, (unsigned)u << 16);
}

// Fused prep.
// Blocks [0,4096): exp-transpose tiles -> kbT[i*N+l]=bf16(exp(-x[l*M+i])).
// Blocks [4096,4104): hr shift-table: plane s holds hrs[s][k] = bf16(h[4095-k-s])
//   (0 for k+s>4095; 128-elem pad so diag-tile overreads stay in-bounds).
//   A[j][l] = w*h[j-l] is then a single ALIGNED 16-B read per chunk:
//   chunk (j, l0c..l0c+7) = hrs[s][(4095-j-s)+l0c ..+7], s=(4095-j)&7 -- the
//   s-plane absorbs the per-row misalignment. Tm (32 MB) is GONE.
__global__ __launch_bounds__(256)
void prep_kernel(const float* __restrict__ x, const float* __restrict__ h,
                 unsigned short* __restrict__ kbT, unsigned short* __restrict__ hrs) {
  __shared__ __align__(16) unsigned short smem[64 * 66];  // 8448 B
  const int bid = (int)blockIdx.x;
  const int tid = threadIdx.x;

  if (bid < 4096) {
    // ---- exp-transpose 64x64 tile ----
    unsigned short (*tileT)[66] = (unsigned short(*)[66])smem;  // [i][l]
    const int i0 = (bid & 63) * 64, l0 = (bid >> 6) * 64;
    const int ci = (tid & 15) * 4;
    const int r0 = tid >> 4;
#pragma unroll
    for (int rr = 0; rr < 4; ++rr) {
      const int l = l0 + r0 + rr * 16;
      const float4 xv = *reinterpret_cast<const float4*>(&x[(size_t)l * M + i0 + ci]);
      const int lr = r0 + rr * 16;
      tileT[ci + 0][lr] = f2bf(__expf(-xv.x));
      tileT[ci + 1][lr] = f2bf(__expf(-xv.y));
      tileT[ci + 2][lr] = f2bf(__expf(-xv.z));
      tileT[ci + 3][lr] = f2bf(__expf(-xv.w));
    }
    __syncthreads();
    // Coalesced readout: lanes (ch=tid&7) cover one 128-B row contiguously.
    const int ch = tid & 7;
#pragma unroll
    for (int s = 0; s < 2; ++s) {
      const int ir = (tid >> 3) + s * 32;
      bf16x8 v = *reinterpret_cast<const bf16x8*>(&tileT[ir][ch * 8]);
      *reinterpret_cast<bf16x8*>(&kbT[(size_t)(i0 + ir) * N + l0 + ch * 8]) = v;
    }
  } else {
    // ---- one shift-plane of the reversed-h table ----
    const int s = bid - 4096;
    unsigned short* pl = hrs + (size_t)s * HRS_STRIDE;
    for (int c = tid; c < HRS_STRIDE / 8; c += 256) {
      const int k0 = c * 8;
      unsigned short e[8];
#pragma unroll
      for (int m = 0; m < 8; ++m) {
        const int idx = 4095 - (k0 + m) - s;
        e[m] = (idx >= 0) ? f2bf(h[idx]) : (unsigned short)0;
      }
      uint4 pk;
      pk.x = (unsigned)e[0] | ((unsigned)e[1] << 16);
      pk.y = (unsigned)e[2] | ((unsigned)e[3] << 16);
      pk.z = (unsigned)e[4] | ((unsigned)e[5] << 16);
      pk.w = (unsigned)e[6] | ((unsigned)e[7] << 16);
      *reinterpret_cast<uint4*>(&pl[k0]) = pk;
    }
  }
}

__device__ __forceinline__ void gld16(void* lds, const void* g) {
  __builtin_amdgcn_global_load_lds(
      (const __attribute__((address_space(1))) void*)g,
      (__attribute__((address_space(3))) void*)lds, 16, 0, 0);
}

// Paired triangular GEMM, proven R0 structure (77 us: 2 blocks/CU, independent
// barrier groups, BK=64, split-barrier dbuf, vmcnt(8)) with A GENERATED from the
// 67-KB hr shift-table instead of fetched from a 32-MB Tm:
//  - per stage: 4 B gld16 (unchanged) + 4 A table-loads (pipelined ONE TILE
//    AHEAD, T14 issue-early/write-late) + 4 ds_write_b128 to the same swizzled
//    LDS layout. Values are bit-identical to the old Tm path.
//  - vmcnt(8) after stageB still certifies exactly tile t's B (queue order:
//    [B(t)][A(t+1)][B(t+1)]; writeA's register dependency drains A(t+1)).
//  - lgkmcnt(0) before barrier #1 publishes the A ds_writes.
//  - weight/mask edges (l>j -> 0, l==j -> 1.5x, l==0 -> 0.5x) touch only the
//    two diagonal K-tiles per band (+ the l==0 chunk), amortized ~0.
// Fragment reads / MFMA / epilogue are byte-identical to the 77-us kernel.
__global__ __launch_bounds__(256)
void gemm_tri_kernel(const unsigned short* __restrict__ hrs,
                     const unsigned short* __restrict__ Bt,
                     const float* __restrict__ fe,
                     float* __restrict__ out) {
  __shared__ __align__(16) unsigned short sm[4 * 8192];  // 64 KB

  const int tid = threadIdx.x;
  const int wave = tid >> 6, lane = tid & 63;
  const int wr = wave >> 1, wc = wave & 1;
  const int lo16 = lane & 15, hi4 = lane >> 4;
  const int i0 = blockIdx.x * BN;
  const int p = (int)blockIdx.y;
  const int sw = lo16 & 7;  // read swizzle key

  const size_t strideB = (size_t)N * 2;  // 8192 B per matrix row

  // staging geometry (unchanged): row srow, pre-swizzled chunk gq
  const int srow = tid >> 3;
  const int gq = ((tid & 7) ^ (srow & 7)) * 16;

  auto stageB = [&](int t, int buf) {
    const char* Bbase = (const char*)Bt + (size_t)i0 * strideB + (size_t)t * 128;
    char* BsB = (char*)sm + 32768 + buf * 16384;
#pragma unroll
    for (int pp = 0; pp < 4; ++pp)
      gld16(BsB + pp * 4096 + wave * 1024,
            Bbase + (size_t)(srow + pp * 32) * strideB + gq);
  };

#pragma unroll 1
  for (int ph = 0; ph < 2; ++ph) {
    const int by = ph ? (31 - p) : p;
    const int j0 = by * BM;
    const int nIter = 2 * by + 2;  // causal K-bound

    // A-source: aptr[pp] + t*128 = aligned 16-B chunk for row j, tile t, chunk gq
    const char* aptr[4];
    int jr[4];
#pragma unroll
    for (int pp = 0; pp < 4; ++pp) {
      const int j = j0 + srow + pp * 32;
      jr[pp] = j;
      const int s = (4095 - j) & 7;
      aptr[pp] = (const char*)hrs + (size_t)s * (HRS_STRIDE * 2)
                 + (size_t)(4095 - j - s) * 2 + gq;
    }

    uint4 a0[4], a1[4];  // two named reg-sets (no runtime indexing -> no scratch)
    auto loadA = [&](int t, uint4* ar) {
#pragma unroll
      for (int pp = 0; pp < 4; ++pp)
        ar[pp] = *reinterpret_cast<const uint4*>(aptr[pp] + (size_t)t * 128);
    };
    auto writeA = [&](int t, const uint4* ar, int buf) {
      char* AsB = (char*)sm + buf * 16384;
      const bool diag = (t >= 2 * by);       // last two K-tiles hold the diagonal
      const int l0c = t * 64 + (gq >> 1);
#pragma unroll
      for (int pp = 0; pp < 4; ++pp) {
        uint4 v = ar[pp];
        if (diag) {
          const int j = jr[pp];
          unsigned short e[8];
          e[0] = (unsigned short)v.x; e[1] = (unsigned short)(v.x >> 16);
          e[2] = (unsigned short)v.y; e[3] = (unsigned short)(v.y >> 16);
          e[4] = (unsigned short)v.z; e[5] = (unsigned short)(v.z >> 16);
          e[6] = (unsigned short)v.w; e[7] = (unsigned short)(v.w >> 16);
#pragma unroll
          for (int m = 0; m < 8; ++m) {
            const int l = l0c + m;
            if (l > j) {
              e[m] = 0;
            } else {
              float wt = 1.0f + (l == j ? 0.5f : 0.0f) - (l == 0 ? 0.5f : 0.0f);
              if (wt != 1.0f) e[m] = f2bf(wt * bf2f(e[m]));
            }
          }
          v.x = (unsigned)e[0] | ((unsigned)e[1] << 16);
          v.y = (unsigned)e[2] | ((unsigned)e[3] << 16);
          v.z = (unsigned)e[4] | ((unsigned)e[5] << 16);
          v.w = (unsigned)e[6] | ((unsigned)e[7] << 16);
        } else if (t == 0 && gq == 0) {
          // l==0 halving (non-diagonal bands; by==0 is covered by the diag path)
          unsigned short e0 = (unsigned short)v.x;
          e0 = f2bf(0.5f * bf2f(e0));
          v.x = (v.x & 0xffff0000u) | e0;
        }
        *reinterpret_cast<uint4*>(AsB + pp * 4096 + tid * 16) = v;
      }
    };

    f32x4 acc[4][4] = {};

    // prologue: B(0) staged; A(0) loaded+written (one-time full drain); A(1) loaded
    stageB(0, 0);
    loadA(0, a0);
    writeA(0, a0, 0);
    loadA(1, a1);

#pragma unroll 1
    for (int t = 0; t < nIter; ++t) {
      const int cur = t & 1;
      if (t + 1 < nIter) {
        stageB(t + 1, cur ^ 1);
        asm volatile("s_waitcnt vmcnt(8)" ::: "memory");  // tile t's B landed
        if (t & 1) writeA(t + 1, a0, cur ^ 1); else writeA(t + 1, a1, cur ^ 1);
        if (t + 2 < nIter) { if (t & 1) loadA(t + 2, a1); else loadA(t + 2, a0); }
      } else {
        asm volatile("s_waitcnt vmcnt(0)" ::: "memory");  // last tile: full drain
      }
      asm volatile("s_waitcnt lgkmcnt(0)" ::: "memory");  // publish A ds_writes
      __builtin_amdgcn_s_barrier();

      const char* AsC = (const char*)sm + cur * 16384;
      const char* BsC = (const char*)sm + 32768 + cur * 16384;
#pragma unroll
      for (int h2 = 0; h2 < 2; ++h2) {
        bf16x8 af[4], bfr[4];
#pragma unroll
        for (int mt = 0; mt < 4; ++mt) {
          const int row = wr * 64 + mt * 16 + lo16;
          const int q = (h2 * 4 + hi4) ^ sw;
          af[mt] = *reinterpret_cast<const bf16x8*>(AsC + row * 128 + q * 16);
        }
#pragma unroll
        for (int nt = 0; nt < 4; ++nt) {
          const int row = wc * 64 + nt * 16 + lo16;
          const int q = (h2 * 4 + hi4) ^ sw;
          bfr[nt] = *reinterpret_cast<const bf16x8*>(BsC + row * 128 + q * 16);
        }
#pragma unroll
        for (int mt = 0; mt < 4; ++mt) {
#pragma unroll
          for (int nt = 0; nt < 4; ++nt) {
            acc[mt][nt] = __builtin_amdgcn_mfma_f32_16x16x32_bf16(
                af[mt], bfr[nt], acc[mt][nt], 0, 0, 0);
          }
        }
      }
      __builtin_amdgcn_s_barrier();  // all reads of buf `cur` done before overwrite
    }

    // Epilogue: plain stores, out = fe[j] - DT*acc.
#pragma unroll
    for (int mt = 0; mt < 4; ++mt) {
      const int jb = j0 + wr * 64 + mt * 16 + hi4 * 4;
      const float4 fev = *reinterpret_cast<const float4*>(&fe[jb]);
      const float fes[4] = {fev.x, fev.y, fev.z, fev.w};
#pragma unroll
      for (int nt = 0; nt < 4; ++nt) {
        const int i = i0 + wc * 64 + nt * 16 + lo16;
#pragma unroll
        for (int r = 0; r < 4; ++r) {
          out[(size_t)(jb + r) * M + i] = fmaf(-DT, acc[mt][nt][r], fes[r]);
        }
      }
    }
  }
}

extern "C" void kernel_launch(void* const* d_in, const int* in_sizes, int n_in,
                              void* d_out, int out_size, void* d_ws, size_t ws_size,
                              hipStream_t stream) {
  const float* x  = (const float*)d_in[0];
  const float* fe = (const float*)d_in[1];
  const float* h  = (const float*)d_in[2];
  float* out = (float*)d_out;

  const size_t matBytes = (size_t)N * N * sizeof(unsigned short);  // 32 MiB (kbT)
  const size_t hrsBytes = (size_t)8 * HRS_STRIDE * sizeof(unsigned short);
  if (ws_size < matBytes + hrsBytes) return;

  unsigned short* kbT = (unsigned short*)d_ws;
  unsigned short* hrs = (unsigned short*)((char*)d_ws + matBytes);

  prep_kernel<<<4104, 256, 0, stream>>>(x, h, kbT, hrs);
  gemm_tri_kernel<<<dim3(M / BN, 16), 256, 0, stream>>>(hrs, kbT, fe, out);
}

// Round 13
// 180.204 us; speedup vs baseline: 1.1342x; 1.1342x over previous
//
#include <hip/hip_runtime.h>
#include <cstdint>
#include <cstddef>

#define N 4096
#define M 4096
#define DT 0.01f

#define BM 128
#define BN 128
#define BK 64   // K elements staged per barrier pair (2 MFMA half-phases)

#define HRS_STRIDE 4224  // shorts per shift-plane (4096 + 128 pad); 8448 B, 16-B aligned

typedef short bf16x8 __attribute__((ext_vector_type(8)));
typedef float f32x4 __attribute__((ext_vector_type(4)));

__device__ __forceinline__ unsigned short f2bf(float f) {
  unsigned u = __builtin_bit_cast(unsigned, f);
  return (unsigned short)((u + 0x7fffu + ((u >> 16) & 1u)) >> 16);  // RNE
}
__device__ __forceinline__ float bf2f(unsigned short u) {
  return __builtin_bit_cast(float, (unsigned)u << 16);
}

// Fused prep.
// Blocks [0,4096): exp-transpose tiles -> kbT[i*N+l]=bf16(exp(-x[l*M+i])).
// Blocks [4096,4104): hr shift-table: plane s holds hrs[s][k] = bf16(h[4095-k-s])
//   (0 for k+s>4095, incl. 128-elem pad). For row j, s=(4095-j)&7: the aligned
//   16-B chunk at hrs[s] + ((4095-j)&~7) + l0 holds h[j-l], ZERO for l>j --
//   i.e. the causally-masked UNWEIGHTED Toeplitz row, directly gld16-able.
//   (Validated on-harness in round 10.) Tm (32 MB) and prep mode-B are GONE;
//   the l==j/l==0 weights are rank-1 epilogue corrections in the gemm.
__global__ __launch_bounds__(256)
void prep_kernel(const float* __restrict__ x, const float* __restrict__ h,
                 unsigned short* __restrict__ kbT, unsigned short* __restrict__ hrs) {
  __shared__ __align__(16) unsigned short smem[64 * 66];  // 8448 B
  const int bid = (int)blockIdx.x;
  const int tid = threadIdx.x;

  if (bid < 4096) {
    // ---- exp-transpose 64x64 tile ----
    unsigned short (*tileT)[66] = (unsigned short(*)[66])smem;  // [i][l]
    const int i0 = (bid & 63) * 64, l0 = (bid >> 6) * 64;
    const int ci = (tid & 15) * 4;
    const int r0 = tid >> 4;
#pragma unroll
    for (int rr = 0; rr < 4; ++rr) {
      const int l = l0 + r0 + rr * 16;
      const float4 xv = *reinterpret_cast<const float4*>(&x[(size_t)l * M + i0 + ci]);
      const int lr = r0 + rr * 16;
      tileT[ci + 0][lr] = f2bf(__expf(-xv.x));
      tileT[ci + 1][lr] = f2bf(__expf(-xv.y));
      tileT[ci + 2][lr] = f2bf(__expf(-xv.z));
      tileT[ci + 3][lr] = f2bf(__expf(-xv.w));
    }
    __syncthreads();
    // Coalesced readout: lanes (ch=tid&7) cover one 128-B row contiguously.
    const int ch = tid & 7;
#pragma unroll
    for (int s = 0; s < 2; ++s) {
      const int ir = (tid >> 3) + s * 32;
      bf16x8 v = *reinterpret_cast<const bf16x8*>(&tileT[ir][ch * 8]);
      *reinterpret_cast<bf16x8*>(&kbT[(size_t)(i0 + ir) * N + l0 + ch * 8]) = v;
    }
  } else {
    // ---- one shift-plane of the reversed-h table ----
    const int s = bid - 4096;
    unsigned short* pl = hrs + (size_t)s * HRS_STRIDE;
    for (int c = tid; c < HRS_STRIDE / 8; c += 256) {
      const int k0 = c * 8;
      unsigned short e[8];
#pragma unroll
      for (int m = 0; m < 8; ++m) {
        const int idx = 4095 - (k0 + m) - s;
        e[m] = (idx >= 0) ? f2bf(h[idx]) : (unsigned short)0;
      }
      uint4 pk;
      pk.x = (unsigned)e[0] | ((unsigned)e[1] << 16);
      pk.y = (unsigned)e[2] | ((unsigned)e[3] << 16);
      pk.z = (unsigned)e[4] | ((unsigned)e[5] << 16);
      pk.w = (unsigned)e[6] | ((unsigned)e[7] << 16);
      *reinterpret_cast<uint4*>(&pl[k0]) = pk;
    }
  }
}

__device__ __forceinline__ void gld16(void* lds, const void* g) {
  __builtin_amdgcn_global_load_lds(
      (const __attribute__((address_space(1))) void*)g,
      (__attribute__((address_space(3))) void*)lds, 16, 0, 0);
}

// Paired triangular GEMM: the PROVEN 77-us R0 loop, byte-identical schedule
// (2 blocks/CU independent barrier groups, BK=64, split-barrier dbuf, vmcnt(8),
// 8 gld16/wave/stage) -- only the A gld16 SOURCE now points into the 67-KB hrs
// table (per-lane global address; L1/L2-resident) instead of the 32-MB Tm.
// The table rows are causally masked but UNWEIGHTED; the l==j (x1.5) and l==0
// (x0.5) Tm weights become rank-1 epilogue corrections:
//   out = fe[j] - DT*acc - (0.5*DT*h[0])*k[j,i] + (0.5*DT*k[0,i])*h[j]
// k[j,i] is harvested from the last two B-tiles STILL IN LDS after the K-loop
// (diagonal band == last 128 staged columns; buf = wr); k[0,i] is 4 L2-hot
// scalar loads at kernel start; h[j] one float4 per mt. NOTHING added to the
// hot loop (round-10 lesson: +4 ds_write/lgkmcnt in-loop cost 32 us).
__global__ __launch_bounds__(256)
void gemm_tri_kernel(const unsigned short* __restrict__ hrs,
                     const unsigned short* __restrict__ Bt,
                     const float* __restrict__ fe,
                     const float* __restrict__ h,
                     float* __restrict__ out) {
  __shared__ __align__(16) unsigned short sm[4 * 8192];  // 64 KB

  const int tid = threadIdx.x;
  const int wave = tid >> 6, lane = tid & 63;
  const int wr = wave >> 1, wc = wave & 1;
  const int lo16 = lane & 15, hi4 = lane >> 4;
  const int i0 = blockIdx.x * BN;
  const int p = (int)blockIdx.y;
  const int sw = lo16 & 7;  // read swizzle key (== row&7 for this lane's rows)

  const size_t strideB = (size_t)N * 2;  // 8192 B per matrix row

  // staging: chunk c = pp*256+tid; row=c>>3, phys chunk=c&7, global chunk=(c&7)^(row&7)
  const int srow = tid >> 3;
  const int gq = ((tid & 7) ^ (srow & 7)) * 16;

  // epilogue constants (hoisted; L2-hot after first blocks)
  const float h0 = h[0];
  const float cA = -0.5f * DT * h0;   // coeff of k[j,i]
  float cB[4];                        // coeff of h[j], per nt
#pragma unroll
  for (int nt = 0; nt < 4; ++nt) {
    const int i = i0 + wc * 64 + nt * 16 + lo16;
    cB[nt] = 0.5f * DT * bf2f(Bt[(size_t)i * N]);   // 0.5*DT*k[0,i]
  }

#pragma unroll 1
  for (int ph = 0; ph < 2; ++ph) {
    const int by = ph ? (31 - p) : p;
    const int j0 = by * BM;
    const int nIter = 2 * by + 2;  // causal K-bound

    // A source: aA[pp] + t*128 = aligned 16-B chunk (row j0+srow+pp*32, chunk gq)
    const char* aA[4];
#pragma unroll
    for (int pp = 0; pp < 4; ++pp) {
      const int j = j0 + srow + pp * 32;
      const int s = (4095 - j) & 7;
      aA[pp] = (const char*)hrs + (size_t)s * (HRS_STRIDE * 2)
               + (size_t)((4095 - j) & ~7) * 2 + gq;
    }

    // 8 gld16 per wave per stage, A/B interleaved (identical schedule to R0)
    auto stage = [&](int t, int buf) {
      const char* Bbase = (const char*)Bt + (size_t)i0 * strideB + (size_t)t * 128;
      char* AsB = (char*)sm + buf * 16384;
      char* BsB = (char*)sm + 32768 + buf * 16384;
#pragma unroll
      for (int pp = 0; pp < 4; ++pp) {
        gld16(AsB + pp * 4096 + wave * 1024, aA[pp] + (size_t)t * 128);
        gld16(BsB + pp * 4096 + wave * 1024,
              Bbase + (size_t)(srow + pp * 32) * strideB + gq);
      }
    };

    f32x4 acc[4][4] = {};

    __syncthreads();       // prior phase's epilogue LDS reads done before restage
    stage(0, 0);           // prologue

#pragma unroll 1
    for (int t = 0; t < nIter; ++t) {
      const int cur = t & 1;
      if (t + 1 < nIter) {
        stage(t + 1, cur ^ 1);
        asm volatile("s_waitcnt vmcnt(8)" ::: "memory");  // tile t landed; t+1 in flight
      } else {
        asm volatile("s_waitcnt vmcnt(0)" ::: "memory");  // last tile: full drain
      }
      __builtin_amdgcn_s_barrier();

      const char* AsC = (const char*)sm + cur * 16384;
      const char* BsC = (const char*)sm + 32768 + cur * 16384;
#pragma unroll
      for (int h2 = 0; h2 < 2; ++h2) {
        bf16x8 af[4], bfr[4];
#pragma unroll
        for (int mt = 0; mt < 4; ++mt) {
          const int row = wr * 64 + mt * 16 + lo16;
          const int q = (h2 * 4 + hi4) ^ sw;
          af[mt] = *reinterpret_cast<const bf16x8*>(AsC + row * 128 + q * 16);
        }
#pragma unroll
        for (int nt = 0; nt < 4; ++nt) {
          const int row = wc * 64 + nt * 16 + lo16;
          const int q = (h2 * 4 + hi4) ^ sw;
          bfr[nt] = *reinterpret_cast<const bf16x8*>(BsC + row * 128 + q * 16);
        }
#pragma unroll
        for (int mt = 0; mt < 4; ++mt) {
#pragma unroll
          for (int nt = 0; nt < 4; ++nt) {
            acc[mt][nt] = __builtin_amdgcn_mfma_f32_16x16x32_bf16(
                af[mt], bfr[nt], acc[mt][nt], 0, 0, 0);
          }
        }
      }
      __builtin_amdgcn_s_barrier();  // all reads of buf `cur` done before next overwrite
    }

    // Epilogue. B-bufs still hold k[l][i] for l in [j0, j0+128): buf = wr.
    // out = fe[j] - DT*acc + cA*k[j,i] + cB[nt]*h[j].
    const char* BsH = (const char*)sm + 32768 + wr * 16384;
#pragma unroll
    for (int mt = 0; mt < 4; ++mt) {
      const int jb = j0 + wr * 64 + mt * 16 + hi4 * 4;
      const float4 fev = *reinterpret_cast<const float4*>(&fe[jb]);
      const float4 hjv = *reinterpret_cast<const float4*>(&h[jb]);
      const float fes[4] = {fev.x, fev.y, fev.z, fev.w};
      const float hjs[4] = {hjv.x, hjv.y, hjv.z, hjv.w};
      const int kk = mt * 16 + hi4 * 4;          // local col within the wr-tile
#pragma unroll
      for (int nt = 0; nt < 4; ++nt) {
        const int row = wc * 64 + nt * 16 + lo16;  // B LDS row for this i
        const ushort4 kv = *reinterpret_cast<const ushort4*>(
            BsH + row * 128 + (((kk >> 3) ^ sw) * 16) + (kk & 7) * 2);
        const unsigned short ks[4] = {kv.x, kv.y, kv.z, kv.w};
        const int i = i0 + wc * 64 + nt * 16 + lo16;
#pragma unroll
        for (int r = 0; r < 4; ++r) {
          float o = fmaf(-DT, acc[mt][nt][r], fes[r]);
          o = fmaf(cA, bf2f(ks[r]), o);
          o = fmaf(cB[nt], hjs[r], o);
          out[(size_t)(jb + r) * M + i] = o;
        }
      }
    }
  }
}

extern "C" void kernel_launch(void* const* d_in, const int* in_sizes, int n_in,
                              void* d_out, int out_size, void* d_ws, size_t ws_size,
                              hipStream_t stream) {
  const float* x  = (const float*)d_in[0];
  const float* fe = (const float*)d_in[1];
  const float* h  = (const float*)d_in[2];
  float* out = (float*)d_out;

  const size_t matBytes = (size_t)N * N * sizeof(unsigned short);  // 32 MiB (kbT)
  const size_t hrsBytes = (size_t)8 * HRS_STRIDE * sizeof(unsigned short);
  if (ws_size < matBytes + hrsBytes) return;

  unsigned short* kbT = (unsigned short*)d_ws;
  unsigned short* hrs = (unsigned short*)((char*)d_ws + matBytes);

  prep_kernel<<<4104, 256, 0, stream>>>(x, h, kbT, hrs);
  gemm_tri_kernel<<<dim3(M / BN, 16), 256, 0, stream>>>(hrs, kbT, fe, h, out);
}